// Round 8
// baseline (147.313 us; speedup 1.0000x reference)
//
#include <hip/hip_runtime.h>
#include <math.h>

// (N, Cin, Cout, S, H, W) = (4, 256, 256, 512, 64, 64)
#define NB 4
#define CC 256
#define SS 512
#define NL 6
#define SLOT_HW 65536   // 128 KB per weight slot, MFMA-A-fragment-packed
// ws layout (halfwords): slots 0..6 (conv + 6x mod_w[l]) = [0, 458752)
//   g table float[6144] at halfword offset 458752 (byte 917504)
#define G_OFF_HW   (7*SLOT_HW)

typedef __attribute__((ext_vector_type(8))) short s16x8;
typedef __attribute__((ext_vector_type(4))) float f32x4;
typedef __attribute__((ext_vector_type(2))) float f32x2;

// keep a 128-bit vector live (forces the load to complete here, not at use)
#define PIN(v) asm volatile("" :: "v"(v))

__device__ __forceinline__ unsigned short f2bf(float f) {
    unsigned u = __builtin_bit_cast(unsigned, f);
    u += 0x7FFFu + ((u >> 16) & 1u);
    return (unsigned short)(u >> 16);
}
// packed RNE f32->bf16 pair: dst[15:0]=cvt(lo), dst[31:16]=cvt(hi)
__device__ __forceinline__ unsigned cvt_pk_bf16(float lo, float hi) {
    unsigned r;
    asm("v_cvt_pk_bf16_f32 %0, %1, %2" : "=v"(r) : "v"(lo), "v"(hi));
    return r;
}
// gelu_exact(x) ~= x*sigmoid(1.5957691216*(x+0.044715x^3)), |err|<3e-3
__device__ __forceinline__ float gelu_fast(float x) {
    float u = x * (1.0f + 0.044715f * x * x);
    float e = __expf(-1.5957691216f * u);
    return x * __builtin_amdgcn_rcpf(1.0f + e);
}

// Fragment-packed weight layout, per 256x256 GEMM slot (128 KB):
// fragment f = (m>>4)*8 + (k>>5); inside: halfword offset
//   ((k>>3)&3)*128 + (m&15)*8 + (k&7)
// wave A-fragment read = slot + f*512 + lane*8 (16 B/lane contiguous).

// ---------------------------------------------------------------------------
// Prep: g-factorization.  wmod rows are uniformly scaled mod_w rows:
//   h = normalize(mod_w*(s+1)) @ y1  ==  g[l,b,m] * (mod_w[l] @ y1),
//   g = t*rsqrt(t^2*Q + eps), t = s[b,m]+1, Q[l,m] = sum_k mod_w[l][m,k]^2.
// => only 7 batch-independent A-slots (conv + 6 mod_w) + 6144-float g table.
__global__ __launch_bounds__(256) void prep_kernel(
    const float* __restrict__ y, const float* __restrict__ aw,
    const float* __restrict__ ab, const float* __restrict__ mw,
    const float* __restrict__ cw, unsigned short* __restrict__ wsBF)
{
    int w = threadIdx.x >> 6, lane = threadIdx.x & 63;
    float* gtab = (float*)(wsBF + G_OFF_HW);

    if (blockIdx.x < 448) {            // slot packing: row = slot*256 + m
        int row = blockIdx.x*4 + w;    // 0..1791
        int sl  = row >> 8, m = row & 255;
        const float* src = (sl == 0) ? (cw + (size_t)m*CC)
                                     : (mw + ((size_t)(sl-1)*CC + m)*CC);
        unsigned short* dst = wsBF + (size_t)sl*SLOT_HW;
#pragma unroll
        for (int u = 0; u < 4; ++u) {
            int k = lane + 64*u;
            int f = (m >> 4)*8 + (k >> 5);
            int hw = f*512 + ((k >> 3) & 3)*128 + (m & 15)*8 + (k & 7);
            dst[hw] = f2bf(src[k]);
        }
        return;
    }

    int r  = (blockIdx.x - 448)*4 + w; // 0..1535 = (layer, out-channel)
    int pl = r >> 8, po = r & 255;

    const float* awr = aw + (size_t)(pl*CC + po)*SS;
    float s[4] = {0.f, 0.f, 0.f, 0.f};
#pragma unroll
    for (int j = 0; j < 8; ++j) {
        int idx = lane + 64*j;
        float a = awr[idx];
#pragma unroll
        for (int b = 0; b < 4; ++b) s[b] += a * y[(size_t)b*SS + idx];
    }
    const float* mwr = mw + ((size_t)pl*CC + po)*CC;
    float qs = 0.f;
#pragma unroll
    for (int u = 0; u < 4; ++u) { float v = mwr[lane + 64*u]; qs += v*v; }
#pragma unroll
    for (int off = 32; off; off >>= 1) {
#pragma unroll
        for (int b = 0; b < 4; ++b) s[b] += __shfl_xor(s[b], off);
        qs += __shfl_xor(qs, off);
    }
    float abv = ab[pl*CC + po];
    if (lane < 4) {
        float t = s[lane] + abv + 1.0f;
        gtab[pl*1024 + lane*256 + po] = t * (1.0f / sqrtf(t*t*qs + 1e-8f));
    }
}

// ---------------------------------------------------------------------------
// Fused: one block = (batch, 16-px quarter-strip, all 256 channels).
// Grid 1024, 512 thr, 40960 B LDS -> 4 blocks/CU = 8 waves/SIMD (2x the TLP
// of the previous 68KB/2-block shape; kernel was latency-bound with all pipes
// <25%). launch_bounds(512,8) caps VGPR at 64 (required for 8 waves/SIMD).
// Wave w owns m=[32w,32w+32), n=16. A-prefetch = 3-slot ring (24 VGPR).
#define BFRAG16(buf, kq, kcl) \
    (lds + (buf)*8192 + ((kq)*2 + (kcl))*1024)

__global__ __launch_bounds__(512, 8) void fused_kernel(
    const float* __restrict__ x, const float* __restrict__ cb,
    const unsigned short* __restrict__ wsBF, float* __restrict__ out)
{
    // LDS 40960 B: layer-B dbuf [0,16K) | conv region @16384:
    //   xS f32[256][24] (24576 B) during conv staging, then S2 f32[256][18]
    //   (18432 B) in the single-pass epilogue (xS dead by then).
    __shared__ __align__(16) unsigned char lds[40960];
    float* xS = (float*)(lds + 16384);
    float* S2 = (float*)(lds + 16384);
    const float* gtab = (const float*)(wsBF + G_OFF_HW);

    const int tid  = threadIdx.x;
    const int lane = tid & 63;
    const int w    = tid >> 6;     // wave 0..7: owns m-rows [32w, 32w+32)
    const int l15  = lane & 15;
    const int q    = lane >> 4;    // 0..3

    // blockIdx&7 -> XCD round-robin; b on 2 XCDs each (x[b] ~L2-resident)
    const int b       = blockIdx.x & 3;          // batch
    const int quarter = (blockIdx.x >> 2) & 3;   // 16-px quarter of strip
    const int strip   = blockIdx.x >> 4;         // 0..63 source row
    const int n0      = strip*64 + quarter*16;

    float y1[2][4], y2[2][4];
    f32x4 acc[2];
    acc[0] = 0; acc[1] = 0;

    // ---------------- conv GEMM:  acc = cw @ x[b] ----------------
    // issue x loads (HBM) first, then A ring slots 0,1 (L2)
    float4 xr[2];
#pragma unroll
    for (int p = 0; p < 2; ++p) {
        int row = (tid >> 2) + 128*p, c4 = (tid & 3) * 4;
        xr[p] = *(const float4*)&x[((size_t)(b*CC + row))*4096 + n0 + c4];
    }
    s16x8 aA[3][2];
#pragma unroll
    for (int p = 0; p < 2; ++p)
#pragma unroll
    for (int t = 0; t < 2; ++t)
        aA[p][t] = *(const s16x8*)(wsBF + (size_t)(((2*w+t)*8 + p)*512) + lane*8);

#pragma unroll
    for (int p = 0; p < 2; ++p) {      // land x into LDS
        int row = (tid >> 2) + 128*p, c4 = (tid & 3) * 4;
        *(float4*)&xS[row*24 + c4] = xr[p];
    }
    __syncthreads();
    {   // transpose-read -> bf16 -> conv-B frags (buf0); per-wave write is
        // exactly lane*16 within its 1KB frag (conflict-free)
        int n = tid & 15, k0 = (tid >> 4) * 8;
        float v[8];
#pragma unroll
        for (int i = 0; i < 8; ++i) v[i] = xS[(k0+i)*24 + n];
        uint4 hv;
        hv.x = cvt_pk_bf16(v[0], v[1]); hv.y = cvt_pk_bf16(v[2], v[3]);
        hv.z = cvt_pk_bf16(v[4], v[5]); hv.w = cvt_pk_bf16(v[6], v[7]);
        int kq = k0 >> 6, kcl = (k0 >> 5) & 1, qq = (k0 >> 3) & 3;
        *(uint4*)(BFRAG16(0,kq,kcl) + (16*qq + n)*16) = hv;
    }
    PIN(aA[0][0]); PIN(aA[0][1]); PIN(aA[1][0]); PIN(aA[1][1]);
    __syncthreads();
    {   // 8-step MFMA, ring-3 A prefetch (slot (s+2)%3 loaded at step s)
        const unsigned short* slot = wsBF;
        __builtin_amdgcn_s_setprio(1);
#pragma unroll
        for (int step = 0; step < 8; ++step) {
            if (step < 6) {
#pragma unroll
                for (int t = 0; t < 2; ++t)
                    aA[(step+2)%3][t] = *(const s16x8*)(slot + (size_t)(((2*w+t)*8 + step+2)*512) + lane*8);
            }
            s16x8 bh = *(const s16x8*)(BFRAG16(0, step>>1, step&1) + lane*16);
            acc[0] = __builtin_amdgcn_mfma_f32_16x16x32_bf16(aA[step%3][0], bh, acc[0], 0, 0, 0);
            acc[1] = __builtin_amdgcn_mfma_f32_16x16x32_bf16(aA[step%3][1], bh, acc[1], 0, 0, 0);
        }
        __builtin_amdgcn_s_setprio(0);
    }

    // conv epilogue, single pass via S2[256][18] (xS dead; fenced above).
    // x1[c]=conv[c>>1]+cb, x2[c]=conv[128+(c>>1)]+cb
    {
        float4 cbv[2];
#pragma unroll
        for (int t = 0; t < 2; ++t)
            cbv[t] = *(const float4*)&cb[32*w + 16*t + 4*q];
#pragma unroll
        for (int t = 0; t < 2; ++t)
#pragma unroll
        for (int r = 0; r < 4; ++r) {
            int m = 32*w + 16*t + 4*q + r;
            S2[m*18 + l15] = acc[t][r] + cbv[t][r];
        }
    }
    __syncthreads();
#pragma unroll
    for (int t = 0; t < 2; ++t)
#pragma unroll
    for (int r = 0; r < 4; ++r) {
        int c = 32*w + 16*t + 4*q + r, h = c >> 1;
        float a  = S2[h*18 + l15];
        float bb = S2[(128 + h)*18 + l15];
        y1[t][r] = a + bb;             // x1 + x2
        y2[t][r] = bb;                 // x2
    }
    // layer-0 staging (buf0) safe: all waves passed the barrier above only
    // after finishing their conv MFMA (all buf0 reads done).

    // ---------------- 6 layers: ONE barrier per layer (B dbuf) --------------
    for (int l = 0; l < NL; ++l) {
        const int buf = l & 1;
        const unsigned short* slot = wsBF + (size_t)(1 + l)*SLOT_HW; // batch-indep
        acc[0] = 0; acc[1] = 0;

        // A ring slots 0,1 issued first (L2 latency hides under B-stage)
#pragma unroll
        for (int p = 0; p < 2; ++p)
#pragma unroll
        for (int t = 0; t < 2; ++t)
            aA[p][t] = *(const s16x8*)(slot + (size_t)(((2*w+t)*8 + p)*512) + lane*8);

        // stage B (bf16) from y1 regs: wave w's rows = k-slice [32w,32w+32)
        {
            int kq = w >> 1, kcl = w & 1, jb = 4*(q & 1);
#pragma unroll
            for (int t = 0; t < 2; ++t) {
                int qq = 2*t + (q >> 1);
                uint2 hv;
                hv.x = cvt_pk_bf16(y1[t][0], y1[t][1]);
                hv.y = cvt_pk_bf16(y1[t][2], y1[t][3]);
                *(uint2*)(BFRAG16(buf,kq,kcl) + (16*qq + l15)*16 + jb*2) = hv;
            }
        }
        PIN(aA[0][0]); PIN(aA[0][1]); PIN(aA[1][0]); PIN(aA[1][1]);
        __syncthreads();
        __builtin_amdgcn_s_setprio(1);
#pragma unroll
        for (int step = 0; step < 8; ++step) {
            if (step < 6) {
#pragma unroll
                for (int t = 0; t < 2; ++t)
                    aA[(step+2)%3][t] = *(const s16x8*)(slot + (size_t)(((2*w+t)*8 + step+2)*512) + lane*8);
            }
            s16x8 bh = *(const s16x8*)(BFRAG16(buf, step>>1, step&1) + lane*16);
            acc[0] = __builtin_amdgcn_mfma_f32_16x16x32_bf16(aA[step%3][0], bh, acc[0], 0, 0, 0);
            acc[1] = __builtin_amdgcn_mfma_f32_16x16x32_bf16(aA[step%3][1], bh, acc[1], 0, 0, 0);
        }
        __builtin_amdgcn_s_setprio(0);

        float4 gv[2];
#pragma unroll
        for (int t = 0; t < 2; ++t)
            gv[t] = *(const float4*)&gtab[l*1024 + b*256 + 32*w + 16*t + 4*q];

        if (l < NL - 1) {
            // h = g*acc; y2 += gelu(h); y1 += y2 for next layer
#pragma unroll
            for (int t = 0; t < 2; ++t)
#pragma unroll
            for (int r = 0; r < 4; ++r) {
                y2[t][r] += gelu_fast(acc[t][r] * gv[t][r]);
                y1[t][r] += y2[t][r];
            }
        } else {
            // LAST layer: fuse epilogue into the 2x2-upsample store
#pragma unroll
            for (int t = 0; t < 2; ++t)
#pragma unroll
            for (int r = 0; r < 4; ++r) {
                float yf = y2[t][r] + gelu_fast(acc[t][r] * gv[t][r]);
                float v  = 0.5f*(y1[t][r] + yf);
                int ch  = 32*w + 16*t + 4*q + r;
                int wpx = quarter*16 + l15;        // 0..63 source col
                f32x2 vv = {v, v};
                size_t base = (((size_t)(b*CC + ch)*128 + 2*strip))*128 + 2*wpx;
                __builtin_nontemporal_store(vv, (f32x2*)&out[base]);
                __builtin_nontemporal_store(vv, (f32x2*)&out[base + 128]);
            }
        }
    }
}

extern "C" void kernel_launch(void* const* d_in, const int* in_sizes, int n_in,
                              void* d_out, int out_size, void* d_ws, size_t ws_size,
                              hipStream_t stream) {
    const float* x  = (const float*)d_in[0];
    const float* y  = (const float*)d_in[1];
    const float* cw = (const float*)d_in[2];
    const float* cb = (const float*)d_in[3];
    const float* aw = (const float*)d_in[4];
    const float* ab = (const float*)d_in[5];
    const float* mw = (const float*)d_in[6];
    float* out = (float*)d_out;

    unsigned short* wsBF = (unsigned short*)d_ws;   // 7 slots + g table < 1 MB

    prep_kernel<<<832, 256, 0, stream>>>(y, aw, ab, mw, cw, wsBF);
    fused_kernel<<<1024, 512, 0, stream>>>(x, cb, wsBF, out);
}

// Round 9
// 118.208 us; speedup vs baseline: 1.2462x; 1.2462x over previous
//
#include <hip/hip_runtime.h>
#include <math.h>

// (N, Cin, Cout, S, H, W) = (4, 256, 256, 512, 64, 64)
#define NB 4
#define CC 256
#define SS 512
#define NL 6
#define SLOT_HW 65536   // 128 KB per weight slot, MFMA-A-fragment-packed
// ws layout (halfwords): slots 0..6 (conv + 6x mod_w[l]) = [0, 458752)
//   g table float[6144] at halfword offset 458752 (byte 917504)
#define G_OFF_HW   (7*SLOT_HW)

typedef __attribute__((ext_vector_type(8))) short s16x8;
typedef __attribute__((ext_vector_type(4))) float f32x4;
typedef __attribute__((ext_vector_type(2))) float f32x2;

__device__ __forceinline__ unsigned short f2bf(float f) {
    unsigned u = __builtin_bit_cast(unsigned, f);
    u += 0x7FFFu + ((u >> 16) & 1u);
    return (unsigned short)(u >> 16);
}
// packed RNE f32->bf16 pair
__device__ __forceinline__ unsigned cvt_pk_bf16(float lo, float hi) {
    unsigned r;
    asm("v_cvt_pk_bf16_f32 %0, %1, %2" : "=v"(r) : "v"(lo), "v"(hi));
    return r;
}
// gelu_exact(x) ~= x*sigmoid(1.5957691216*(x+0.044715x^3)), |err|<3e-3
__device__ __forceinline__ float gelu_fast(float x) {
    float u = x * (1.0f + 0.044715f * x * x);
    float e = __expf(-1.5957691216f * u);
    return x * __builtin_amdgcn_rcpf(1.0f + e);
}
// un-rematerializable prefetch load: result registers MUST be kept
__device__ __forceinline__ s16x8 aload(const unsigned short* p) {
    s16x8 r;
    asm volatile("global_load_dwordx4 %0, %1, off" : "=v"(r) : "v"(p));
    return r;
}

// ---------------------------------------------------------------------------
// Prep (unchanged): g-factorization -> 7 batch-independent A-slots + g table.
__global__ __launch_bounds__(256) void prep_kernel(
    const float* __restrict__ y, const float* __restrict__ aw,
    const float* __restrict__ ab, const float* __restrict__ mw,
    const float* __restrict__ cw, unsigned short* __restrict__ wsBF)
{
    int w = threadIdx.x >> 6, lane = threadIdx.x & 63;
    float* gtab = (float*)(wsBF + G_OFF_HW);

    if (blockIdx.x < 448) {            // slot packing: row = slot*256 + m
        int row = blockIdx.x*4 + w;    // 0..1791
        int sl  = row >> 8, m = row & 255;
        const float* src = (sl == 0) ? (cw + (size_t)m*CC)
                                     : (mw + ((size_t)(sl-1)*CC + m)*CC);
        unsigned short* dst = wsBF + (size_t)sl*SLOT_HW;
#pragma unroll
        for (int u = 0; u < 4; ++u) {
            int k = lane + 64*u;
            int f = (m >> 4)*8 + (k >> 5);
            int hw = f*512 + ((k >> 3) & 3)*128 + (m & 15)*8 + (k & 7);
            dst[hw] = f2bf(src[k]);
        }
        return;
    }

    int r  = (blockIdx.x - 448)*4 + w; // 0..1535 = (layer, out-channel)
    int pl = r >> 8, po = r & 255;

    const float* awr = aw + (size_t)(pl*CC + po)*SS;
    float s[4] = {0.f, 0.f, 0.f, 0.f};
#pragma unroll
    for (int j = 0; j < 8; ++j) {
        int idx = lane + 64*j;
        float a = awr[idx];
#pragma unroll
        for (int b = 0; b < 4; ++b) s[b] += a * y[(size_t)b*SS + idx];
    }
    const float* mwr = mw + ((size_t)pl*CC + po)*CC;
    float qs = 0.f;
#pragma unroll
    for (int u = 0; u < 4; ++u) { float v = mwr[lane + 64*u]; qs += v*v; }
#pragma unroll
    for (int off = 32; off; off >>= 1) {
#pragma unroll
        for (int b = 0; b < 4; ++b) s[b] += __shfl_xor(s[b], off);
        qs += __shfl_xor(qs, off);
    }
    float abv = ab[pl*CC + po];
    if (lane < 4) {
        float t = s[lane] + abv + 1.0f;
        gtab[pl*1024 + lane*256 + po] = t * (1.0f / sqrtf(t*t*qs + 1e-8f));
    }
}

// ---------------------------------------------------------------------------
// Fused: 512 blocks x 512 thr, 2 blocks/CU. TRUE A-prefetch: asm-volatile
// global_load_dwordx4 (not rematerializable) + counted vmcnt waits tied to
// the A regs via "+v" (MFMA cannot hoist above). Pre-MFMA barriers are RAW
// s_barrier + lgkmcnt(0) so the prefetch stays in flight across them
// (__syncthreads would drain vmcnt to 0).
#define BFRAGL(buf, kq, nt, kcl) \
    (lds + (buf)*16384 + ((((kq)*2 + (nt))*2 + (kcl)))*1024)

// issue both t-halves of A slot p (literal p)
#define ISSUE(p) { \
    aS[p][0] = aload(slot + (size_t)(((2*w+0)*8 + (p))*512) + lane*8); \
    aS[p][1] = aload(slot + (size_t)(((2*w+1)*8 + (p))*512) + lane*8); }
// wait until <=N vmem outstanding; ties slot st's regs so dependent MFMAs
// cannot be scheduled above the wait
#define WAITA(N, st) asm volatile("s_waitcnt vmcnt(" #N ")" \
    : "+v"(aS[st][0]), "+v"(aS[st][1]))
#define STEPX(st) { \
    s16x8 b0 = *(const s16x8*)(BFRAGL(buf,(st)>>1,0,(st)&1) + lane*16); \
    s16x8 b1 = *(const s16x8*)(BFRAGL(buf,(st)>>1,1,(st)&1) + lane*16); \
    acc[0][0] = __builtin_amdgcn_mfma_f32_16x16x32_bf16(aS[st][0], b0, acc[0][0],0,0,0); \
    acc[1][0] = __builtin_amdgcn_mfma_f32_16x16x32_bf16(aS[st][1], b0, acc[1][0],0,0,0); \
    acc[0][1] = __builtin_amdgcn_mfma_f32_16x16x32_bf16(aS[st][0], b1, acc[0][1],0,0,0); \
    acc[1][1] = __builtin_amdgcn_mfma_f32_16x16x32_bf16(aS[st][1], b1, acc[1][1],0,0,0); \
}
#define MFMA_PHASE() \
    ISSUE(5); WAITA(10,0); STEPX(0); \
    ISSUE(6); WAITA(10,1); STEPX(1); \
    ISSUE(7); WAITA(10,2); STEPX(2); \
    WAITA(8,3);  STEPX(3); \
    WAITA(6,4);  STEPX(4); \
    WAITA(4,5);  STEPX(5); \
    WAITA(2,6);  STEPX(6); \
    WAITA(0,7);  STEPX(7);
#define RAW_BARRIER() { \
    asm volatile("s_waitcnt lgkmcnt(0)" ::: "memory"); \
    __builtin_amdgcn_s_barrier(); }

__global__ __launch_bounds__(512, 4) void fused_kernel(
    const float* __restrict__ x, const float* __restrict__ cb,
    const unsigned short* __restrict__ wsBF, float* __restrict__ out)
{
    // LDS 75776 B: layer-B dbuf [0,32K) | conv region @32768: xS f32[256][36]
    // (36864 B), overlaid by S2 f32[256][33] in the epilogue | g LDS @69632
    // (6 KB, this block's batch slice of gtab). 2 blocks/CU (151.5 KB).
    __shared__ __align__(16) unsigned char lds[75776];
    float* xS = (float*)(lds + 32768);
    float* S2 = (float*)(lds + 32768);
    float* gS = (float*)(lds + 69632);
    const float* gtab = (const float*)(wsBF + G_OFF_HW);

    const int tid  = threadIdx.x;
    const int lane = tid & 63;
    const int w    = tid >> 6;     // wave 0..7: owns m-rows [32w, 32w+32)
    const int l15  = lane & 15;
    const int q    = lane >> 4;    // 0..3

    // XCD swizzle: blockIdx%8 -> (batch, half) per XCD
    const int bswz  = blockIdx.x & 7;
    const int b     = bswz >> 1;               // 0..3
    const int half  = bswz & 1;                // 0..1
    const int strip = blockIdx.x >> 3;         // 0..63
    const int n0    = strip * 64 + half * 32;  // 32-px window

    float y1[2][2][4], y2[2][2][4];
    f32x4 acc[2][2];
    s16x8 aS[8][2];

    // ---------------- conv GEMM:  acc = cw @ x[b] ----------------
#pragma unroll
    for (int t = 0; t < 2; ++t)
#pragma unroll
        for (int s = 0; s < 2; ++s) acc[t][s] = 0;

    // g slice -> LDS (C++ VMEM, fully waited by compiler before our asm)
    if (tid < 384) {
        int gl = tid >> 6, gm = (tid & 63) * 4;
        float4 gvv = *(const float4*)&gtab[gl*1024 + b*256 + gm];
        *(float4*)&gS[gl*256 + gm] = gvv;
    }
    // x window -> LDS, coalesced
#pragma unroll
    for (int p = 0; p < 4; ++p) {
        int row = (tid >> 3) + 64*p, c4 = (tid & 7) * 4;
        float4 v = *(const float4*)&x[((size_t)(b*CC + row))*4096 + n0 + c4];
        *(float4*)&xS[row*36 + c4] = v;
    }
    // fence: keep compiler's x/g loads+waits above our asm issues
    asm volatile("" ::: "memory");
    {
        const unsigned short* slot = wsBF;
#pragma unroll
        for (int p = 0; p < 5; ++p) ISSUE(p);
        RAW_BARRIER();                 // xS staged (lgkm only; A stays in flight)
        {   // transpose-read (conflict-free) -> bf16 -> ALL conv-B frags (buf0)
            int n = tid & 31, k0 = (tid >> 5) * 16;
            int nt = n >> 4, n15 = n & 15;
#pragma unroll
            for (int j = 0; j < 4; ++j) {
                int k = k0 + 4*j;
                float v0 = xS[(k+0)*36 + n], v1 = xS[(k+1)*36 + n];
                float v2 = xS[(k+2)*36 + n], v3 = xS[(k+3)*36 + n];
                uint2 hv; hv.x = cvt_pk_bf16(v0, v1); hv.y = cvt_pk_bf16(v2, v3);
                int kq = k >> 6, kcl = (k >> 5) & 1, qq = (k >> 3) & 3, jb = k & 7;
                *(uint2*)(BFRAGL(0,kq,nt,kcl) + (16*qq + n15)*16 + jb*2) = hv;
            }
        }
        RAW_BARRIER();                 // frags ready
        const int buf = 0;
        __builtin_amdgcn_s_setprio(1);
        MFMA_PHASE();
        __builtin_amdgcn_s_setprio(0);
    }

    // conv epilogue, single pass via S2[256][33] (vmcnt=0 here; __syncthreads ok)
#pragma unroll
    for (int t = 0; t < 2; ++t)
#pragma unroll
    for (int s = 0; s < 2; ++s)
#pragma unroll
    for (int r = 0; r < 4; ++r) {
        int m  = 32*w + 16*t + 4*q + r;
        int nl = 16*s + l15;
        S2[m*33 + nl] = acc[t][s][r] + cb[m];
    }
    __syncthreads();
#pragma unroll
    for (int t = 0; t < 2; ++t)
#pragma unroll
    for (int s = 0; s < 2; ++s)
#pragma unroll
    for (int r = 0; r < 4; ++r) {
        int c  = 32*w + 16*t + 4*q + r;
        int nl = 16*s + l15;
        float a  = S2[(c >> 1)*33 + nl];
        float bb = S2[(128 + (c >> 1))*33 + nl];
        y1[t][s][r] = a + bb;          // x1 + x2
        y2[t][s][r] = bb;              // x2
    }

    // ---------------- 6 layers: ONE raw barrier per layer (B dbuf) ----------
    for (int l = 0; l < NL; ++l) {
        const int buf = l & 1;
        const unsigned short* slot = wsBF + (size_t)(1 + l)*SLOT_HW;
#pragma unroll
        for (int t = 0; t < 2; ++t)
#pragma unroll
            for (int s = 0; s < 2; ++s) acc[t][s] = 0;

        asm volatile("" ::: "memory");
#pragma unroll
        for (int p = 0; p < 5; ++p) ISSUE(p);   // A prefetch, stays in flight

        // stage B (bf16) from y1 regs: wave w's rows = k-slice [32w,32w+32)
        {
            int kq = w >> 1, kcl = w & 1, jb = 4*(q & 1);
#pragma unroll
            for (int t = 0; t < 2; ++t) {
                int qq = 2*t + (q >> 1);
#pragma unroll
                for (int s = 0; s < 2; ++s) {
                    uint2 hv;
                    hv.x = cvt_pk_bf16(y1[t][s][0], y1[t][s][1]);
                    hv.y = cvt_pk_bf16(y1[t][s][2], y1[t][s][3]);
                    *(uint2*)(BFRAGL(buf,kq,s,kcl) + (16*qq + l15)*16 + jb*2) = hv;
                }
            }
        }
        RAW_BARRIER();                 // B ready; A prefetch still in flight
        __builtin_amdgcn_s_setprio(1);
        MFMA_PHASE();
        __builtin_amdgcn_s_setprio(0);

        // g from LDS (lgkm path only; no vmcnt interference)
        float4 gv[2];
#pragma unroll
        for (int t = 0; t < 2; ++t)
            gv[t] = *(const float4*)&gS[l*256 + 32*w + 16*t + 4*q];

        if (l < NL - 1) {
#pragma unroll
            for (int t = 0; t < 2; ++t)
#pragma unroll
            for (int s = 0; s < 2; ++s)
#pragma unroll
            for (int r = 0; r < 4; ++r) {
                y2[t][s][r] += gelu_fast(acc[t][s][r] * gv[t][r]);
                y1[t][s][r] += y2[t][s][r];
            }
        } else {
            // LAST layer: fuse epilogue into the 2x2-upsample store
#pragma unroll
            for (int t = 0; t < 2; ++t)
#pragma unroll
            for (int s = 0; s < 2; ++s)
#pragma unroll
            for (int r = 0; r < 4; ++r) {
                float yf = y2[t][s][r] + gelu_fast(acc[t][s][r] * gv[t][r]);
                float v  = 0.5f*(y1[t][s][r] + yf);
                int ch  = 32*w + 16*t + 4*q + r;
                int wpx = half*32 + 16*s + l15;       // 0..63 source col
                f32x2 vv = {v, v};
                size_t base = (((size_t)(b*CC + ch)*128 + 2*strip))*128 + 2*wpx;
                __builtin_nontemporal_store(vv, (f32x2*)&out[base]);
                __builtin_nontemporal_store(vv, (f32x2*)&out[base + 128]);
            }
        }
    }
}

extern "C" void kernel_launch(void* const* d_in, const int* in_sizes, int n_in,
                              void* d_out, int out_size, void* d_ws, size_t ws_size,
                              hipStream_t stream) {
    const float* x  = (const float*)d_in[0];
    const float* y  = (const float*)d_in[1];
    const float* cw = (const float*)d_in[2];
    const float* cb = (const float*)d_in[3];
    const float* aw = (const float*)d_in[4];
    const float* ab = (const float*)d_in[5];
    const float* mw = (const float*)d_in[6];
    float* out = (float*)d_out;

    unsigned short* wsBF = (unsigned short*)d_ws;   // 7 slots + g table < 1 MB

    prep_kernel<<<832, 256, 0, stream>>>(y, aw, ab, mw, cw, wsBF);
    fused_kernel<<<512, 512, 0, stream>>>(x, cb, wsBF, out);
}